// Round 1
// baseline (1301.361 us; speedup 1.0000x reference)
//
#include <hip/hip_runtime.h>
#include <cstdint>
#include <cstddef>

#define N_    16
#define DIM_  2048
#define RF_   256
#define PN_   64
#define TOPK_ 10
#define HW_   128
#define KFULL (DIM_*HW_)   /* 262144 */
#define KMV   (TOPK_*RF_)  /* 2560 */

// ---------------------------------------------------------------------------
// Kernel 1: partial dot products x·p and partial ||p||^2, chunked over K.
// 256 blocks x 128 threads; block b owns k-range [b*1024, b*1024+1024).
// Deterministic partial buffers (no atomics -> no hot-line serialization).
// ---------------------------------------------------------------------------
__global__ __launch_bounds__(128)
void dist_partial_kernel(const float* __restrict__ x, const float* __restrict__ proto,
                         float* __restrict__ pdot, float* __restrict__ ppn) {
  __shared__ alignas(16) float xl[16][132];
  __shared__ alignas(16) float pl[64][132];
  const int t  = threadIdx.x;
  const int b  = blockIdx.x;
  const int n0 = t & 7;        // owns n0, n0+8
  const int pb = t >> 3;       // 0..15 -> owns pb, pb+16, pb+32, pb+48
  float acc[2][4] = {};
  float pn = 0.f;

  for (int sc = 0; sc < 8; ++sc) {
    const int k0 = b * 1024 + sc * 128;
    // stage x tile: 16 rows x 128 (512 float4 / 128 thr = 4 each)
#pragma unroll
    for (int it = 0; it < 4; ++it) {
      int f = it * 128 + t;
      int row = f >> 5, s4 = f & 31;
      float4 v = *(const float4*)(x + (size_t)row * KFULL + k0 + s4 * 4);
      *(float4*)&xl[row][s4 * 4] = v;
    }
    // stage p tile: 64 rows x 128 (2048 float4 / 128 thr = 16 each)
#pragma unroll
    for (int it = 0; it < 16; ++it) {
      int f = it * 128 + t;
      int row = f >> 5, s4 = f & 31;
      float4 v = *(const float4*)(proto + (size_t)row * KFULL + k0 + s4 * 4);
      *(float4*)&pl[row][s4 * 4] = v;
    }
    __syncthreads();

#pragma unroll 4
    for (int k = 0; k < 128; k += 4) {
      float4 xa = *(float4*)&xl[n0][k];
      float4 xb = *(float4*)&xl[n0 + 8][k];
      float4 pp0 = *(float4*)&pl[pb][k];
      float4 pp1 = *(float4*)&pl[pb + 16][k];
      float4 pp2 = *(float4*)&pl[pb + 32][k];
      float4 pp3 = *(float4*)&pl[pb + 48][k];
      acc[0][0] += xa.x*pp0.x + xa.y*pp0.y + xa.z*pp0.z + xa.w*pp0.w;
      acc[0][1] += xa.x*pp1.x + xa.y*pp1.y + xa.z*pp1.z + xa.w*pp1.w;
      acc[0][2] += xa.x*pp2.x + xa.y*pp2.y + xa.z*pp2.z + xa.w*pp2.w;
      acc[0][3] += xa.x*pp3.x + xa.y*pp3.y + xa.z*pp3.z + xa.w*pp3.w;
      acc[1][0] += xb.x*pp0.x + xb.y*pp0.y + xb.z*pp0.z + xb.w*pp0.w;
      acc[1][1] += xb.x*pp1.x + xb.y*pp1.y + xb.z*pp1.z + xb.w*pp1.w;
      acc[1][2] += xb.x*pp2.x + xb.y*pp2.y + xb.z*pp2.z + xb.w*pp2.w;
      acc[1][3] += xb.x*pp3.x + xb.y*pp3.y + xb.z*pp3.z + xb.w*pp3.w;
    }
    if (t < 64) {
#pragma unroll 4
      for (int k = 0; k < 128; k += 4) {
        float4 pv = *(float4*)&pl[t][k];
        pn += pv.x*pv.x + pv.y*pv.y + pv.z*pv.z + pv.w*pv.w;
      }
    }
    __syncthreads();
  }

#pragma unroll
  for (int i = 0; i < 2; ++i)
#pragma unroll
    for (int g = 0; g < 4; ++g)
      pdot[(size_t)b * 1024 + (n0 + i * 8) * 64 + pb + g * 16] = acc[i][g];
  if (t < 64) ppn[(size_t)b * 64 + t] = pn;
}

// ---------------------------------------------------------------------------
// Kernel 2: reduce partials -> dist[n][p] = ||p||^2 - 2 x·p (x-norm constant
// per n, irrelevant for ranking), then wave argmin x10 -> idx[n][10].
// 16 blocks (one per n) x 256 threads.
// ---------------------------------------------------------------------------
__global__ __launch_bounds__(256)
void select_kernel(const float* __restrict__ pdot, const float* __restrict__ ppn,
                   int* __restrict__ idx) {
  __shared__ float redd[4][64];
  __shared__ float redn[4][64];
  const int n = blockIdx.x;
  const int t = threadIdx.x;
  const int p = t & 63, grp = t >> 6;
  float sd = 0.f, sn = 0.f;
  for (int q = 0; q < 64; ++q) {
    int bb = grp * 64 + q;
    sd += pdot[(size_t)bb * 1024 + n * 64 + p];
    sn += ppn[(size_t)bb * 64 + p];
  }
  redd[grp][p] = sd;
  redn[grp][p] = sn;
  __syncthreads();
  if (t < 64) {
    float dot = redd[0][t] + redd[1][t] + redd[2][t] + redd[3][t];
    float pnm = redn[0][t] + redn[1][t] + redn[2][t] + redn[3][t];
    float dval = pnm - 2.f * dot;
    for (int j = 0; j < TOPK_; ++j) {
      float v = dval; int vi = t;
#pragma unroll
      for (int m = 32; m >= 1; m >>= 1) {
        float ov = __shfl_xor(v, m, 64);
        int   oi = __shfl_xor(vi, m, 64);
        if (ov < v || (ov == v && oi < vi)) { v = ov; vi = oi; }
      }
      if (t == 0) idx[n * TOPK_ + j] = vi;
      if (t == vi) dval = 3.4e38f;
    }
  }
}

// ---------------------------------------------------------------------------
// Unified fp32 GEMM: C[b][o][s] = sum_k W[o][k] * X[b][k][s], S = 128 fixed.
// Block tile 128(O) x 128(S), BK=16, 256 threads, 8x8 per-thread tile.
// MODE 0: plain store (xp)
// MODE 1: X gathered from xp via idx; epilogue relu(0.5*in + (1-1/262144)*acc)
// MODE 2: epilogue instance-norm over s (full S in block)
// MODE 3: epilogue out = in * (1 + sigmoid(acc))
// ---------------------------------------------------------------------------
#define BO  128
#define BK  16
#define WLD 132

template <int MODE>
__global__ __launch_bounds__(256)
void gemm_kernel(const float* __restrict__ W, const float* __restrict__ X,
                 float* __restrict__ Out, const float* __restrict__ inputs,
                 const int* __restrict__ idxp, const float* __restrict__ xp,
                 int K, int O) {
  __shared__ alignas(16) float Wl[BK][WLD];
  __shared__ alignas(16) float Xl[BK][HW_];
  __shared__ int ids[TOPK_];

  const int t  = threadIdx.x;
  const int b  = blockIdx.y;
  const int o0 = blockIdx.x * BO;
  const int ts = t & 15;   // s-group: s0 = ts*8
  const int to = t >> 4;   // o-group: o = o0 + to*8 + i

  if (MODE == 1) {
    if (t < TOPK_) ids[t] = idxp[b * TOPK_ + t];
    __syncthreads();
  }

  float acc[8][8] = {};
  const float* Xb = (MODE == 1) ? nullptr : (X + (size_t)b * K * HW_);

  for (int k0 = 0; k0 < K; k0 += BK) {
    // stage W tile transposed: Wl[k][o], 128 o x 16 k
#pragma unroll
    for (int it = 0; it < 2; ++it) {
      int f = it * 256 + t;         // 0..511
      int o = f >> 2, kq = f & 3;
      float4 v = *(const float4*)(W + (size_t)(o0 + o) * K + k0 + kq * 4);
      Wl[kq * 4 + 0][o] = v.x;
      Wl[kq * 4 + 1][o] = v.y;
      Wl[kq * 4 + 2][o] = v.z;
      Wl[kq * 4 + 3][o] = v.w;
    }
    // stage X tile: Xl[k][s], 16 k x 128 s
#pragma unroll
    for (int it = 0; it < 2; ++it) {
      int f = it * 256 + t;
      int kk = f >> 5, s4 = f & 31;
      const float* row;
      if (MODE == 1) {
        int kg = k0 + kk;
        int j = kg >> 8, r = kg & 255;
        row = xp + ((size_t)ids[j] * RF_ + r) * HW_;
      } else {
        row = Xb + (size_t)(k0 + kk) * HW_;
      }
      *(float4*)&Xl[kk][s4 * 4] = *(const float4*)(row + s4 * 4);
    }
    __syncthreads();

#pragma unroll
    for (int k = 0; k < BK; ++k) {
      float4 xa = *(float4*)&Xl[k][ts * 8];
      float4 xb = *(float4*)&Xl[k][ts * 8 + 4];
      float4 wa = *(float4*)&Wl[k][to * 8];
      float4 wb = *(float4*)&Wl[k][to * 8 + 4];
      float wv[8] = {wa.x, wa.y, wa.z, wa.w, wb.x, wb.y, wb.z, wb.w};
      float xv[8] = {xa.x, xa.y, xa.z, xa.w, xb.x, xb.y, xb.z, xb.w};
#pragma unroll
      for (int i = 0; i < 8; ++i)
#pragma unroll
        for (int j = 0; j < 8; ++j)
          acc[i][j] += wv[i] * xv[j];
    }
    __syncthreads();
  }

  // ---------------- epilogue ----------------
  const float CAL = 1.0f - 1.0f / 262144.0f;
  float* outb = Out + (size_t)b * O * HW_;
  const float* inb = inputs ? (inputs + (size_t)b * DIM_ * HW_) : nullptr;

#pragma unroll
  for (int i = 0; i < 8; ++i) {
    const int orow = o0 + to * 8 + i;
    if (MODE == 2) {
      float s = 0.f, s2 = 0.f;
#pragma unroll
      for (int j = 0; j < 8; ++j) { s += acc[i][j]; s2 += acc[i][j] * acc[i][j]; }
#pragma unroll
      for (int m = 1; m < 16; m <<= 1) {
        s  += __shfl_xor(s, m, 64);
        s2 += __shfl_xor(s2, m, 64);
      }
      float mean = s * (1.f / 128.f);
      float var  = s2 * (1.f / 128.f) - mean * mean;
      float rs   = rsqrtf(var + 1e-5f);
#pragma unroll
      for (int j = 0; j < 8; ++j) acc[i][j] = (acc[i][j] - mean) * rs;
    }

    float* op = outb + (size_t)orow * HW_ + ts * 8;
    if (MODE == 0 || MODE == 2) {
      *(float4*)op       = make_float4(acc[i][0], acc[i][1], acc[i][2], acc[i][3]);
      *(float4*)(op + 4) = make_float4(acc[i][4], acc[i][5], acc[i][6], acc[i][7]);
    } else {
      const float* ip = inb + (size_t)orow * HW_ + ts * 8;
      float4 ia = *(const float4*)ip;
      float4 ib = *(const float4*)(ip + 4);
      float iv[8] = {ia.x, ia.y, ia.z, ia.w, ib.x, ib.y, ib.z, ib.w};
      float ov[8];
#pragma unroll
      for (int j = 0; j < 8; ++j) {
        if (MODE == 1) {
          ov[j] = fmaxf(0.f, 0.5f * iv[j] + CAL * acc[i][j]);
        } else { // MODE 3
          float sg = 1.f / (1.f + expf(-acc[i][j]));
          ov[j] = iv[j] * (1.f + sg);
        }
      }
      *(float4*)op       = make_float4(ov[0], ov[1], ov[2], ov[3]);
      *(float4*)(op + 4) = make_float4(ov[4], ov[5], ov[6], ov[7]);
    }
  }
}

// ---------------------------------------------------------------------------
extern "C" void kernel_launch(void* const* d_in, const int* in_sizes, int n_in,
                              void* d_out, int out_size, void* d_ws, size_t ws_size,
                              hipStream_t stream) {
  const float* inputs = (const float*)d_in[0];   // [16,2048,16,8]
  const float* proto  = (const float*)d_in[1];   // [64,2048,16,8]
  const float* w_rf   = (const float*)d_in[2];   // [256,2048]
  const float* w_rfmv = (const float*)d_in[3];   // [2048,2560]
  const float* w_rms  = (const float*)d_in[4];   // [2048,2048]
  const float* w_fuse = (const float*)d_in[5];   // [2048,2048]
  float* out = (float*)d_out;

  float* ws = (float*)d_ws;
  float* pdot = ws;                       // 256*1024 = 262144
  float* ppn  = ws + 262144;              // 256*64   = 16384
  int*   idx  = (int*)(ws + 278528);      // 160 ints
  float* xp   = ws + 278784;              // 64*256*128 = 2097152
  float* mvl  = xp + 2097152;             // 16*2048*128 = 4194304
  float* mva  = mvl + 4194304;            // 16*2048*128 = 4194304

  dist_partial_kernel<<<256, 128, 0, stream>>>(inputs, proto, pdot, ppn);
  select_kernel<<<16, 256, 0, stream>>>(pdot, ppn, idx);

  // xp = w_rf @ proto   [64 batches, O=256, K=2048]
  gemm_kernel<0><<<dim3(2, 64), 256, 0, stream>>>(w_rf, proto, xp,
                                                  nullptr, nullptr, nullptr, 2048, 256);
  // mvl = relu(0.5*in + c*(w_rf_mv @ gather(xp)))  [16 batches, O=2048, K=2560]
  gemm_kernel<1><<<dim3(16, 16), 256, 0, stream>>>(w_rfmv, nullptr, mvl,
                                                   inputs, idx, xp, KMV, DIM_);
  // mva = instnorm(w_rm_s @ mvl)  [16, O=2048, K=2048]
  gemm_kernel<2><<<dim3(16, 16), 256, 0, stream>>>(w_rms, mvl, mva,
                                                   nullptr, nullptr, nullptr, DIM_, DIM_);
  // out = in * (1 + sigmoid(w_fuse @ mva))  [16, O=2048, K=2048]
  gemm_kernel<3><<<dim3(16, 16), 256, 0, stream>>>(w_fuse, mva, out,
                                                   inputs, nullptr, nullptr, DIM_, DIM_);
}

// Round 2
// 446.907 us; speedup vs baseline: 2.9119x; 2.9119x over previous
//
#include <hip/hip_runtime.h>
#include <cstdint>
#include <cstddef>

#define N_    16
#define DIM_  2048
#define RF_   256
#define PN_   64
#define TOPK_ 10
#define HW_   128
#define KFULL (DIM_*HW_)   /* 262144 */
#define KMV   (TOPK_*RF_)  /* 2560 */

#define AS1 __attribute__((address_space(1)))
#define AS3 __attribute__((address_space(3)))

typedef __attribute__((ext_vector_type(8))) short bf16x8;
typedef __attribute__((ext_vector_type(4))) float f32x4;

__device__ __forceinline__ unsigned short f2bf(float f) {
  unsigned u = __builtin_bit_cast(unsigned, f);
  unsigned r = (u + 0x7FFFu + ((u >> 16) & 1u)) >> 16;
  return (unsigned short)r;
}

// ---------------------------------------------------------------------------
// fp32 -> bf16 elementwise convert (weights). n4 = count/4.
// ---------------------------------------------------------------------------
__global__ __launch_bounds__(256)
void cvt_bf16_kernel(const float* __restrict__ s, unsigned short* __restrict__ d, int n4) {
  int i = blockIdx.x * blockDim.x + threadIdx.x;
  int stride = gridDim.x * blockDim.x;
  for (; i < n4; i += stride) {
    float4 v = *(const float4*)(s + (size_t)i * 4);
    ushort4 o;
    o.x = f2bf(v.x); o.y = f2bf(v.y); o.z = f2bf(v.z); o.w = f2bf(v.w);
    *(ushort4*)(d + (size_t)i * 4) = o;
  }
}

// ---------------------------------------------------------------------------
// proto [64][2048][128] fp32 -> protoT [64][128][2048] bf16
// grid (64 p, 64 c-chunks of 32), 256 threads.
// ---------------------------------------------------------------------------
__global__ __launch_bounds__(256)
void transpose_proto_kernel(const float* __restrict__ src, unsigned short* __restrict__ dst) {
  __shared__ float tile[32][129];
  const int p = blockIdx.x;
  const int c0 = blockIdx.y * 32;
  const int t = threadIdx.x;
  const float* sp = src + ((size_t)p * DIM_ + c0) * HW_;
#pragma unroll
  for (int i = 0; i < 4; ++i) {
    int g = i * 256 + t;          // float4 id, 1024 total (32 c x 32 f4)
    int ci = g >> 5, s4 = g & 31;
    float4 v = *(const float4*)(sp + (size_t)ci * HW_ + s4 * 4);
    int sb = s4 * 4;
    tile[ci][sb] = v.x; tile[ci][sb + 1] = v.y; tile[ci][sb + 2] = v.z; tile[ci][sb + 3] = v.w;
  }
  __syncthreads();
  const int s = t >> 1, ch = (t & 1) * 16;
  unsigned short* dp = dst + ((size_t)p * HW_ + s) * DIM_ + c0 + ch;
#pragma unroll
  for (int g = 0; g < 4; ++g) {
    ushort4 pk;
    pk.x = f2bf(tile[ch + g * 4 + 0][s]);
    pk.y = f2bf(tile[ch + g * 4 + 1][s]);
    pk.z = f2bf(tile[ch + g * 4 + 2][s]);
    pk.w = f2bf(tile[ch + g * 4 + 3][s]);
    *(ushort4*)(dp + g * 4) = pk;
  }
}

// ---------------------------------------------------------------------------
// dist partials (fp32, unchanged from round 1 — rank safety requires fp32)
// ---------------------------------------------------------------------------
__global__ __launch_bounds__(128)
void dist_partial_kernel(const float* __restrict__ x, const float* __restrict__ proto,
                         float* __restrict__ pdot, float* __restrict__ ppn) {
  __shared__ alignas(16) float xl[16][132];
  __shared__ alignas(16) float pl[64][132];
  const int t  = threadIdx.x;
  const int b  = blockIdx.x;
  const int n0 = t & 7;
  const int pb = t >> 3;
  float acc[2][4] = {};
  float pn = 0.f;

  for (int sc = 0; sc < 8; ++sc) {
    const int k0 = b * 1024 + sc * 128;
#pragma unroll
    for (int it = 0; it < 4; ++it) {
      int f = it * 128 + t;
      int row = f >> 5, s4 = f & 31;
      float4 v = *(const float4*)(x + (size_t)row * KFULL + k0 + s4 * 4);
      *(float4*)&xl[row][s4 * 4] = v;
    }
#pragma unroll
    for (int it = 0; it < 16; ++it) {
      int f = it * 128 + t;
      int row = f >> 5, s4 = f & 31;
      float4 v = *(const float4*)(proto + (size_t)row * KFULL + k0 + s4 * 4);
      *(float4*)&pl[row][s4 * 4] = v;
    }
    __syncthreads();

#pragma unroll 4
    for (int k = 0; k < 128; k += 4) {
      float4 xa = *(float4*)&xl[n0][k];
      float4 xb = *(float4*)&xl[n0 + 8][k];
      float4 pp0 = *(float4*)&pl[pb][k];
      float4 pp1 = *(float4*)&pl[pb + 16][k];
      float4 pp2 = *(float4*)&pl[pb + 32][k];
      float4 pp3 = *(float4*)&pl[pb + 48][k];
      acc[0][0] += xa.x*pp0.x + xa.y*pp0.y + xa.z*pp0.z + xa.w*pp0.w;
      acc[0][1] += xa.x*pp1.x + xa.y*pp1.y + xa.z*pp1.z + xa.w*pp1.w;
      acc[0][2] += xa.x*pp2.x + xa.y*pp2.y + xa.z*pp2.z + xa.w*pp2.w;
      acc[0][3] += xa.x*pp3.x + xa.y*pp3.y + xa.z*pp3.z + xa.w*pp3.w;
      acc[1][0] += xb.x*pp0.x + xb.y*pp0.y + xb.z*pp0.z + xb.w*pp0.w;
      acc[1][1] += xb.x*pp1.x + xb.y*pp1.y + xb.z*pp1.z + xb.w*pp1.w;
      acc[1][2] += xb.x*pp2.x + xb.y*pp2.y + xb.z*pp2.z + xb.w*pp2.w;
      acc[1][3] += xb.x*pp3.x + xb.y*pp3.y + xb.z*pp3.z + xb.w*pp3.w;
    }
    if (t < 64) {
#pragma unroll 4
      for (int k = 0; k < 128; k += 4) {
        float4 pv = *(float4*)&pl[t][k];
        pn += pv.x*pv.x + pv.y*pv.y + pv.z*pv.z + pv.w*pv.w;
      }
    }
    __syncthreads();
  }

#pragma unroll
  for (int i = 0; i < 2; ++i)
#pragma unroll
    for (int g = 0; g < 4; ++g)
      pdot[(size_t)b * 1024 + (n0 + i * 8) * 64 + pb + g * 16] = acc[i][g];
  if (t < 64) ppn[(size_t)b * 64 + t] = pn;
}

__global__ __launch_bounds__(256)
void select_kernel(const float* __restrict__ pdot, const float* __restrict__ ppn,
                   int* __restrict__ idx) {
  __shared__ float redd[4][64];
  __shared__ float redn[4][64];
  const int n = blockIdx.x;
  const int t = threadIdx.x;
  const int p = t & 63, grp = t >> 6;
  float sd = 0.f, sn = 0.f;
  for (int q = 0; q < 64; ++q) {
    int bb = grp * 64 + q;
    sd += pdot[(size_t)bb * 1024 + n * 64 + p];
    sn += ppn[(size_t)bb * 64 + p];
  }
  redd[grp][p] = sd;
  redn[grp][p] = sn;
  __syncthreads();
  if (t < 64) {
    float dot = redd[0][t] + redd[1][t] + redd[2][t] + redd[3][t];
    float pnm = redn[0][t] + redn[1][t] + redn[2][t] + redn[3][t];
    float dval = pnm - 2.f * dot;
    for (int j = 0; j < TOPK_; ++j) {
      float v = dval; int vi = t;
#pragma unroll
      for (int m = 32; m >= 1; m >>= 1) {
        float ov = __shfl_xor(v, m, 64);
        int   oi = __shfl_xor(vi, m, 64);
        if (ov < v || (ov == v && oi < vi)) { v = ov; vi = oi; }
      }
      if (t == 0) idx[n * TOPK_ + j] = vi;
      if (t == vi) dval = 3.4e38f;
    }
  }
}

// ---------------------------------------------------------------------------
// bf16 MFMA GEMM: C[b][o][s] = sum_k W[o][k] * X[b][s][k]  (X channel-contig)
// BM=64, BN=128(=S), BK=32. 256 thr = 4 waves (2x2), wave = 32(M) x 64(N),
// 2x4 grid of v_mfma_f32_16x16x32_bf16.
// LDS tiles k-quad-major: cell(q, row) = 16B at q*(ROWS*16) + row*16 — makes
// global_load_lds staging lane-contiguous AND ds_read_b128 ~2-way/bank.
// MODE 0: store bf16 T ([s][o]) -> xpT
// MODE 1: B gathered from xpT via idx; relu(0.5*in + CAL*acc); store bf16 T
// MODE 2: instance-norm over s; store bf16 T
// MODE 3: out = in * (1 + sigmoid(acc)); store fp32 [o][s] (d_out)
// ---------------------------------------------------------------------------
#define BM 64
#define BK 32

template <int MODE>
__global__ __launch_bounds__(256, 2)
void mfma_gemm_kernel(const unsigned short* __restrict__ Wb,  // [O][K] bf16
                      const unsigned short* __restrict__ Xb,  // [b][128][K] bf16 (or xpT)
                      void* __restrict__ OutP,
                      const float* __restrict__ inputs,       // fp32 [b][2048][128]
                      const int* __restrict__ idxp,
                      int K, int O, int Ldim) {
  __shared__ unsigned short Al[4 * BM * 8];    // 4 KB
  __shared__ unsigned short Bl[4 * 128 * 8];   // 8 KB
  __shared__ float nsum[2][64], nsq[2][64];    // MODE 2
  __shared__ int ids[TOPK_];

  const int t = threadIdx.x;
  const int w = t >> 6;          // wave 0..3
  const int lane = t & 63;
  const int q = lane >> 4;       // MFMA quad
  const int l15 = lane & 15;
  const int mw = w >> 1, nw = w & 1;
  const int batch = blockIdx.y;
  const int o0 = blockIdx.x * BM;

  if (MODE == 1) {
    if (t < TOPK_) ids[t] = idxp[batch * TOPK_ + t];
    __syncthreads();
  }

  f32x4 acc[2][4] = {};

  for (int k0 = 0; k0 < K; k0 += BK) {
    // ---- stage A tile (quad = w): rows m = lane ----
    {
      const unsigned short* ga = Wb + (size_t)(o0 + lane) * K + k0 + w * 8;
      __builtin_amdgcn_global_load_lds((const AS1 void*)ga,
                                       (AS3 void*)(&Al[w * BM * 8]), 16, 0, 0);
    }
    // ---- stage B tile (quad = w): rows n = half*64 + lane ----
    {
      const unsigned short* base;
      int rowstride;
      if (MODE == 1) {
        base = Xb + (size_t)ids[k0 >> 8] * (HW_ * RF_) + (k0 & 255);
        rowstride = RF_;
      } else {
        base = Xb + (size_t)batch * HW_ * K + k0;
        rowstride = K;
      }
#pragma unroll
      for (int h = 0; h < 2; ++h) {
        const unsigned short* gb = base + (size_t)(h * 64 + lane) * rowstride + w * 8;
        __builtin_amdgcn_global_load_lds((const AS1 void*)gb,
                                         (AS3 void*)(&Bl[w * 1024 + h * 512]), 16, 0, 0);
      }
    }
    __syncthreads();

    bf16x8 af[2], bfr[4];
#pragma unroll
    for (int mt = 0; mt < 2; ++mt)
      af[mt] = *(const bf16x8*)(&Al[q * BM * 8 + (mw * 32 + mt * 16 + l15) * 8]);
#pragma unroll
    for (int nt = 0; nt < 4; ++nt)
      bfr[nt] = *(const bf16x8*)(&Bl[q * 1024 + (nw * 64 + nt * 16 + l15) * 8]);
#pragma unroll
    for (int mt = 0; mt < 2; ++mt)
#pragma unroll
      for (int nt = 0; nt < 4; ++nt)
        acc[mt][nt] = __builtin_amdgcn_mfma_f32_16x16x32_bf16(af[mt], bfr[nt], acc[mt][nt], 0, 0, 0);
    __syncthreads();
  }

  // ---------------- epilogue ----------------
  const float CAL = 1.0f - 1.0f / 262144.0f;

  if (MODE == 2) {
#pragma unroll
    for (int mt = 0; mt < 2; ++mt)
#pragma unroll
      for (int reg = 0; reg < 4; ++reg) {
        float s_ = 0.f, q_ = 0.f;
#pragma unroll
        for (int nt = 0; nt < 4; ++nt) {
          float v = acc[mt][nt][reg];
          s_ += v; q_ += v * v;
        }
#pragma unroll
        for (int m = 1; m < 16; m <<= 1) {
          s_ += __shfl_xor(s_, m, 64);
          q_ += __shfl_xor(q_, m, 64);
        }
        if (l15 == 0) {
          int ol = mw * 32 + mt * 16 + q * 4 + reg;
          nsum[nw][ol] = s_; nsq[nw][ol] = q_;
        }
      }
    __syncthreads();
  }

  if (MODE == 3) {
    float* ofb = (float*)OutP + (size_t)batch * DIM_ * HW_;
    const float* inb = inputs + (size_t)batch * DIM_ * HW_;
#pragma unroll
    for (int mt = 0; mt < 2; ++mt)
#pragma unroll
      for (int nt = 0; nt < 4; ++nt) {
        int o = o0 + mw * 32 + mt * 16 + q * 4;
        int s = nw * 64 + nt * 16 + l15;
        f32x4 v = acc[mt][nt];
#pragma unroll
        for (int g = 0; g < 4; ++g) {
          float in = inb[(size_t)(o + g) * HW_ + s];
          float sg = 1.f / (1.f + expf(-v[g]));
          ofb[(size_t)(o + g) * HW_ + s] = in * (1.f + sg);
        }
      }
  } else {
    unsigned short* ob = (unsigned short*)OutP + (size_t)batch * HW_ * Ldim;
    const float* inb = (MODE == 1) ? inputs + (size_t)batch * DIM_ * HW_ : nullptr;
#pragma unroll
    for (int mt = 0; mt < 2; ++mt) {
      float mean[4], rs[4];
      if (MODE == 2) {
#pragma unroll
        for (int reg = 0; reg < 4; ++reg) {
          int ol = mw * 32 + mt * 16 + q * 4 + reg;
          float ts = nsum[0][ol] + nsum[1][ol];
          float tq = nsq[0][ol] + nsq[1][ol];
          float mn = ts * (1.f / 128.f);
          float vr = tq * (1.f / 128.f) - mn * mn;
          mean[reg] = mn; rs[reg] = rsqrtf(vr + 1e-5f);
        }
      }
#pragma unroll
      for (int nt = 0; nt < 4; ++nt) {
        int o = o0 + mw * 32 + mt * 16 + q * 4;
        int s = nw * 64 + nt * 16 + l15;
        f32x4 v = acc[mt][nt];
        float r[4];
        if (MODE == 0) {
#pragma unroll
          for (int g = 0; g < 4; ++g) r[g] = v[g];
        } else if (MODE == 1) {
          const float* ip = inb + (size_t)o * HW_ + s;
#pragma unroll
          for (int g = 0; g < 4; ++g)
            r[g] = fmaxf(0.f, 0.5f * ip[(size_t)g * HW_] + CAL * v[g]);
        } else { // MODE 2
#pragma unroll
          for (int g = 0; g < 4; ++g) r[g] = (v[g] - mean[g]) * rs[g];
        }
        ushort4 pk;
        pk.x = f2bf(r[0]); pk.y = f2bf(r[1]); pk.z = f2bf(r[2]); pk.w = f2bf(r[3]);
        *(ushort4*)(ob + (size_t)s * Ldim + o) = pk;
      }
    }
  }
}

// ---------------------------------------------------------------------------
extern "C" void kernel_launch(void* const* d_in, const int* in_sizes, int n_in,
                              void* d_out, int out_size, void* d_ws, size_t ws_size,
                              hipStream_t stream) {
  const float* inputs = (const float*)d_in[0];   // [16,2048,16,8]
  const float* proto  = (const float*)d_in[1];   // [64,2048,16,8]
  const float* w_rf   = (const float*)d_in[2];   // [256,2048]
  const float* w_rfmv = (const float*)d_in[3];   // [2048,2560]
  const float* w_rms  = (const float*)d_in[4];   // [2048,2048]
  const float* w_fuse = (const float*)d_in[5];   // [2048,2048]
  float* out = (float*)d_out;

  uint8_t* ws = (uint8_t*)d_ws;
  size_t off = 0;
  auto alloc = [&](size_t bytes) { uint8_t* p = ws + off; off += (bytes + 255) & ~(size_t)255; return p; };

  float* pdot = (float*)alloc(256 * 1024 * 4);                 // 1 MB
  float* ppn  = (float*)alloc(256 * 64 * 4);                   // 64 KB
  int*   idx  = (int*)alloc(256 * 4);
  unsigned short* wrf_b   = (unsigned short*)alloc((size_t)RF_ * DIM_ * 2);     // 1 MB
  unsigned short* wrfmv_b = (unsigned short*)alloc((size_t)DIM_ * KMV * 2);     // 10 MB
  unsigned short* wrms_b  = (unsigned short*)alloc((size_t)DIM_ * DIM_ * 2);    // 8 MB
  unsigned short* wfuse_b = (unsigned short*)alloc((size_t)DIM_ * DIM_ * 2);    // 8 MB
  unsigned short* xpT     = (unsigned short*)alloc((size_t)PN_ * HW_ * RF_ * 2);// 4 MB
  // protoT (33.5 MB) is dead after GEMM1 -> mvlT and mvaT alias into it.
  unsigned short* protoT  = (unsigned short*)alloc((size_t)PN_ * HW_ * DIM_ * 2);
  unsigned short* mvlT = protoT;                                // 8 MB (aliases protoT)
  unsigned short* mvaT = protoT + (size_t)N_ * HW_ * DIM_;      // 8 MB (aliases protoT)

  // weight converts + proto transpose (independent of dist/select)
  cvt_bf16_kernel<<<512, 256, 0, stream>>>(w_rf,   wrf_b,   RF_ * DIM_ / 4);
  cvt_bf16_kernel<<<512, 256, 0, stream>>>(w_rfmv, wrfmv_b, DIM_ * KMV / 4);
  cvt_bf16_kernel<<<512, 256, 0, stream>>>(w_rms,  wrms_b,  DIM_ * DIM_ / 4);
  cvt_bf16_kernel<<<512, 256, 0, stream>>>(w_fuse, wfuse_b, DIM_ * DIM_ / 4);
  transpose_proto_kernel<<<dim3(PN_, DIM_ / 32), 256, 0, stream>>>(proto, protoT);

  dist_partial_kernel<<<256, 128, 0, stream>>>(inputs, proto, pdot, ppn);
  select_kernel<<<16, 256, 0, stream>>>(pdot, ppn, idx);

  // GEMM1: xpT = (w_rf @ proto)^T per p  [M=256, N=128, K=2048] x64
  mfma_gemm_kernel<0><<<dim3(RF_ / BM, PN_), 256, 0, stream>>>(
      wrf_b, protoT, xpT, nullptr, nullptr, DIM_, RF_, RF_);
  // GEMM2: mvlT = relu(0.5*in + c*(w_rf_mv @ gather(xp)))^T  [M=2048,N=128,K=2560] x16
  mfma_gemm_kernel<1><<<dim3(DIM_ / BM, N_), 256, 0, stream>>>(
      wrfmv_b, xpT, mvlT, inputs, idx, KMV, DIM_, DIM_);
  // GEMM3: mvaT = instnorm(w_rm_s @ mvl)^T  [M=2048,N=128,K=2048] x16
  mfma_gemm_kernel<2><<<dim3(DIM_ / BM, N_), 256, 0, stream>>>(
      wrms_b, mvlT, mvaT, nullptr, nullptr, DIM_, DIM_, DIM_);
  // GEMM4: out = in * (1 + sigmoid(w_fuse @ mva))  [M=2048,N=128,K=2048] x16
  mfma_gemm_kernel<3><<<dim3(DIM_ / BM, N_), 256, 0, stream>>>(
      wfuse_b, mvaT, out, inputs, nullptr, DIM_, DIM_, DIM_);
}